// Round 7
// baseline (296.969 us; speedup 1.0000x reference)
//
#include <hip/hip_runtime.h>
#include <cstring>
#include <cstdint>

// Problem constants (fixed by reference)
#define B_TOTAL 8192
#define F_IN    1024
#define U_UNITS 256
#define NACT    16
#define HID     8

typedef float    f32x4  __attribute__((ext_vector_type(4)));
typedef _Float16 half8  __attribute__((ext_vector_type(8)));

// ============================================================================
// MFMA path: fp16 split-2 emulation of fp32 GEMM (3 passes; 2 when A exact).
// Low parts pre-scaled by 2048 (fp16 normal range). Cross terms in acc2@2^-11.
//
// R17: R13 (last known-running kernel, 282us total) + two surgical edits.
// Rounds 5/6 failed with "container failed twice" on the R15 binary (no
// device-side signal; round-4 infra showed 769s pushes). To disambiguate
// infra-vs-content and still test the L2-residency theory:
//  * m-affinity XCD swizzle (bijective): xcd=flat&7, j=flat>>3,
//    m_tile=xcd*8+(j>>5), n_tile=j&31. Concurrent blocks per XCD span ~3 A
//    m-panels (~1.5MB) -> A staged loads (2/3 of bytes) hit the XCD-private
//    L2; per-XCD total A footprint 4MB = one L2 -> A fetched from HBM ~once.
//    (R12's swizzle did the opposite and streamed all of A per XCD.)
//  * staging bases wave-uniform via readfirstlane (R14-proven) -> SGPR adds.
//  Everything else is R13 verbatim: dbuf + __syncthreads K-loop, 48KB stage,
//  launch_bounds(256,4), same epilogue. MFMA pass order unchanged ->
//  bit-identical output (absmax 0.21875).
// ============================================================================

__device__ __forceinline__ void gload_lds16(const _Float16* g, _Float16* l)
{
    // 16B per lane; LDS dest is wave-uniform base + lane*16 (HW-implicit)
    __builtin_amdgcn_global_load_lds(
        (const __attribute__((address_space(1))) void*)g,
        (__attribute__((address_space(3))) void*)l,
        16, 0, 0);
}

// fp32 [R][K] -> packed high/low fp16 [R/16][K/32][64][8]; all three tensors
// in one launch (block ranges) to save inter-dispatch gaps.
__global__ __launch_bounds__(256)
void pack3_kernel(const float* __restrict__ s0, _Float16* __restrict__ d0h, _Float16* __restrict__ d0l,
                  const float* __restrict__ s1, _Float16* __restrict__ d1h, _Float16* __restrict__ d1l,
                  const float* __restrict__ s2, _Float16* __restrict__ d2h, _Float16* __restrict__ d2l)
{
    constexpr int NB0 = (B_TOTAL / 16) * (F_IN / 128);          // 4096
    constexpr int NB1 = (U_UNITS * HID / 16) * (F_IN / 128);    // 1024
    __shared__ float ls[16 * 132];
    int b = blockIdx.x;
    const float* src; _Float16 *dh, *dl; int K, lg;
    if (b < NB0)            { src = s0; dh = d0h; dl = d0l; K = F_IN;    lg = 3; }
    else if (b < NB0 + NB1) { b -= NB0; src = s1; dh = d1h; dl = d1l; K = F_IN; lg = 3; }
    else                    { b -= NB0 + NB1; src = s2; dh = d2h; dl = d2l; K = U_UNITS; lg = 1; }

    const int tid = threadIdx.x;
    const int mt  = b >> lg;
    const int kb  = b & ((1 << lg) - 1);
    const int r0  = mt * 16;

#pragma unroll
    for (int i = 0; i < 2; ++i) {
        const int e = tid + (i << 8);
        const int row = e >> 5;
        const int c4  = e & 31;
        f32x4 v = *reinterpret_cast<const f32x4*>(
            &src[(size_t)(r0 + row) * K + (kb << 7) + (c4 << 2)]);
        *reinterpret_cast<f32x4*>(&ls[row * 132 + (c4 << 2)]) = v;
    }
    __syncthreads();

    const int k8 = tid >> 4, r = tid & 15;
    float x[8];
#pragma unroll
    for (int j = 0; j < 8; ++j) x[j] = ls[r * 132 + (k8 << 3) + j];
    half8 h, l;
#pragma unroll
    for (int j = 0; j < 8; ++j) {
        h[j] = (_Float16)x[j];
        l[j] = (_Float16)((x[j] - (float)h[j]) * 2048.0f);
    }
    const size_t off = (((size_t)mt * (K >> 5)) + (kb << 2) + (k8 >> 2)) * 512
                     + (size_t)(((k8 & 3) << 4) + r) * 8;
    *reinterpret_cast<half8*>(&dh[off]) = h;
    *reinterpret_cast<half8*>(&dl[off]) = l;
}

constexpr int BM = 128, BN = 64;   // 4 waves, wave tile 64x32 (2M x 2N)

template<int K_TOTAL, bool A_SPLIT, bool OUT_TF32>
__global__ __launch_bounds__(256, 4)
void coagent_mfma(const _Float16* __restrict__ Ahg, const _Float16* __restrict__ Alg,
                  const _Float16* __restrict__ Bhg, const _Float16* __restrict__ Blg,
                  const float* __restrict__ b0, const float* __restrict__ W1,
                  const float* __restrict__ b1, const float* __restrict__ W2,
                  const float* __restrict__ b2, void* __restrict__ outp)
{
    // stage buffer (halves): A_SPLIT: Ah[0,4096) Al[4096,8192) Bh[8192,10240)
    // Bl[10240,12288). !A_SPLIT (compact): Ah[0,4096) Bh[4096,6144) Bl[6144,8192).
    constexpr int BUFH  = A_SPLIT ? 12288 : 8192;
    constexpr int BOFFH = A_SPLIT ? 8192 : 4096;
    constexpr int BOFFL = A_SPLIT ? 10240 : 6144;
    constexpr int NCH   = A_SPLIT ? 6 : 4;      // staging chunks per wave

    struct EpiBufs { float Hs[BM][BN + 1]; _Float16 ab[BM * 8]; };
    union SMemU { _Float16 stage[2][BUFH]; EpiBufs epi; };
    __shared__ SMemU sm;

    constexpr int NTK = K_TOTAL >> 5;        // k-tiles (K=32 each); 32 or 8
    constexpr size_t TS = (size_t)NTK * 512; // halves per row-tile

    const int tid  = threadIdx.x;
    const int wave = tid >> 6;
    const int lane = tid & 63;
    const int quad = lane >> 4;
    const int l15  = lane & 15;

    // m-affinity XCD swizzle (bijective on [0,2048)): each XCD owns 8
    // contiguous m-panels; n sweeps fastest within an XCD -> concurrent
    // blocks share ~3 A m-panels (~1.5MB, L2-resident).
    const int flat = blockIdx.y * gridDim.x + blockIdx.x;
    const int xcd  = flat & 7;
    const int j    = flat >> 3;              // 0..255
    const int m0   = ((xcd << 3) | (j >> 5)) * BM;
    const int n0   = (j & 31) * BN;

    const int wmi = wave >> 1, wni = wave & 1;
    const int at  = wmi * 4;                 // A tile base (of 8)
    const int bt  = wni * 2;                 // B tile base (of 4)
    const int wm  = wmi * 64, wn = wni * 32;

    // ---- staging chunk map: NCH chunks per wave. Bases wave-uniform
    // (readfirstlane) -> SGPR arithmetic; lane offset added at call sites.
    const int wave_u = __builtin_amdgcn_readfirstlane(wave);
    const _Float16* gs[NCH];
#pragma unroll
    for (int i = 0; i < NCH; ++i) {
        const int c = wave_u * NCH + i;
        const _Float16* base; int tile;
        if (A_SPLIT) {
            if (c < 8)       { base = Ahg; tile = (m0 >> 4) + c; }
            else if (c < 16) { base = Alg; tile = (m0 >> 4) + (c - 8); }
            else if (c < 20) { base = Bhg; tile = (n0 >> 4) + (c - 16); }
            else             { base = Blg; tile = (n0 >> 4) + (c - 20); }
        } else {
            if (c < 8)       { base = Ahg; tile = (m0 >> 4) + c; }
            else if (c < 12) { base = Bhg; tile = (n0 >> 4) + (c - 8); }
            else             { base = Blg; tile = (n0 >> 4) + (c - 12); }
        }
        gs[i] = base + (size_t)tile * TS;
    }
    const int loff = lane * 8;   // element offset (16B per lane)

    f32x4 acc1[4][2];   // Ah*Bh            (scale 1)
    f32x4 acc2[4][2];   // Al'*Bh + Ah*Bl'  (scale 2^-11)
#pragma unroll
    for (int i = 0; i < 4; ++i)
#pragma unroll
        for (int jj = 0; jj < 2; ++jj) { acc1[i][jj] = {0.f,0.f,0.f,0.f}; acc2[i][jj] = {0.f,0.f,0.f,0.f}; }

    // prologue: stage k-tile 0 into buffer 0
#pragma unroll
    for (int i = 0; i < NCH; ++i)
        gload_lds16(gs[i] + loff, &sm.stage[0][(wave_u * NCH + i) * 512]);
    __syncthreads();

    int cur = 0;
#pragma unroll 1
    for (int kt = 0; kt < NTK; ++kt) {
        // issue next tile's staging loads (in flight across the MFMA phase)
        if (kt + 1 < NTK) {
            _Float16* nb = &sm.stage[cur ^ 1][0];
#pragma unroll
            for (int i = 0; i < NCH; ++i)
                gload_lds16(gs[i] + (size_t)(kt + 1) * 512 + loff,
                            nb + (wave_u * NCH + i) * 512);
        }

        const _Float16* sb = &sm.stage[cur][0];
        half8 af[4], la[4];
#pragma unroll
        for (int mt = 0; mt < 4; ++mt)
            af[mt] = *reinterpret_cast<const half8*>(&sb[(at + mt) * 512 + lane * 8]);
        if constexpr (A_SPLIT) {
#pragma unroll
            for (int mt = 0; mt < 4; ++mt)
                la[mt] = *reinterpret_cast<const half8*>(&sb[4096 + (at + mt) * 512 + lane * 8]);
        }

        // per-nt grouping keeps B frags ephemeral (8 regs); per-acc-element
        // addition order identical to the 3-pass original -> bit-identical.
#pragma unroll
        for (int nt = 0; nt < 2; ++nt) {
            half8 bf = *reinterpret_cast<const half8*>(&sb[BOFFH + (bt + nt) * 512 + lane * 8]);
            half8 lb = *reinterpret_cast<const half8*>(&sb[BOFFL + (bt + nt) * 512 + lane * 8]);
#pragma unroll
            for (int mt = 0; mt < 4; ++mt)
                acc1[mt][nt] = __builtin_amdgcn_mfma_f32_16x16x32_f16(af[mt], bf, acc1[mt][nt], 0, 0, 0);
            if constexpr (A_SPLIT) {
#pragma unroll
                for (int mt = 0; mt < 4; ++mt)
                    acc2[mt][nt] = __builtin_amdgcn_mfma_f32_16x16x32_f16(la[mt], bf, acc2[mt][nt], 0, 0, 0);
            }
#pragma unroll
            for (int mt = 0; mt < 4; ++mt)
                acc2[mt][nt] = __builtin_amdgcn_mfma_f32_16x16x32_f16(af[mt], lb, acc2[mt][nt], 0, 0, 0);
        }

        __syncthreads();   // stage(kt+1) complete + all reads of buf cur done
        cur ^= 1;
    }

    // ---- epilogue: block = 128 rows x 8 units (one octet) ----
#pragma unroll
    for (int mt = 0; mt < 4; ++mt)
#pragma unroll
        for (int nt = 0; nt < 2; ++nt)
#pragma unroll
            for (int r = 0; r < 4; ++r)
                sm.epi.Hs[wm + mt * 16 + quad * 4 + r][wn + nt * 16 + l15] =
                    acc1[mt][nt][r] + acc2[mt][nt][r] * (1.0f / 2048.0f);
    __syncthreads();

    const int ubase = n0 >> 3;
#pragma unroll
    for (int p = 0; p < 4; ++p) {
        const int idx = (p << 8) + tid;
        const int ul = idx >> 7;            // unit 0..7, wave-uniform
        const int bl = idx & 127;           // lane-consecutive batch row
        // pin u as wave-uniform -> weight loads become scalar (SMEM pipe)
        const int u  = __builtin_amdgcn_readfirstlane(ubase + ul);
        const float* __restrict__ b0u = b0 + u * 8;
        const float* __restrict__ W1u = W1 + u * 64;
        const float* __restrict__ b1u = b1 + u * 8;
        const float* __restrict__ W2u = W2 + u * 128;
        const float* __restrict__ b2u = b2 + u * 16;

        float h[HID];
#pragma unroll
        for (int jj = 0; jj < HID; ++jj)
            h[jj] = fmaxf(sm.epi.Hs[bl][ul * 8 + jj] + b0u[jj], 0.f);

        float h2[HID];
#pragma unroll
        for (int g = 0; g < HID; ++g) {
            float s = b1u[g];
#pragma unroll
            for (int jj = 0; jj < HID; ++jj)
                s += h[jj] * W1u[g * 8 + jj];
            h2[g] = fmaxf(s, 0.f);
        }

        float best = b2u[0];
#pragma unroll
        for (int jj = 0; jj < HID; ++jj) best += h2[jj] * W2u[jj];
        int bi = 0;
#pragma unroll
        for (int a = 1; a < NACT; ++a) {
            float s = b2u[a];
#pragma unroll
            for (int jj = 0; jj < HID; ++jj)
                s += h2[jj] * W2u[a * 8 + jj];
            if (s > best) { best = s; bi = a; }   // first-max-wins = np.argmax
        }

        if (OUT_TF32) {
            ((float*)outp)[(size_t)u * B_TOTAL + m0 + bl] = (float)bi;
        } else {
            sm.epi.ab[bl * 8 + ul] = (_Float16)bi;
        }
    }
    if (!OUT_TF32) {
        __syncthreads();
        if (tid < 128) {   // write a0 in PACKED layout (NTK=8 for K=256)
            float4 v = *reinterpret_cast<float4*>(&sm.epi.ab[tid * 8]);
            const int u = ubase;                     // octet base, uniform
            const int b = m0 + tid;
            const size_t off = ((size_t)(b >> 4) * 8 + (u >> 5)) * 512
                             + (size_t)((((u >> 3) & 3) << 4) + (b & 15)) * 8;
            *reinterpret_cast<float4*>(&((_Float16*)outp)[off]) = v;
        }
    }
}

// ============================================================================
// fp32 fallback path (round-1 kernels) — used only if ws_size is too small
// ============================================================================

constexpr int FBM = 128, FBN = 128, FBK = 16;

template<int K_TOTAL, bool X_TRANSPOSED>
__global__ __launch_bounds__(256, 2)
void coagent_kernel(const float* __restrict__ X, const float* __restrict__ W0,
                    const float* __restrict__ b0, const float* __restrict__ W1,
                    const float* __restrict__ b1, const float* __restrict__ W2,
                    const float* __restrict__ b2, float* __restrict__ outT)
{
    struct SMemGemm { float As[FBK][FBM + 4]; float Bs[FBK][FBN + 4]; };
    union SMem { SMemGemm g; float Hs[FBM][65]; };
    __shared__ SMem sm;

    const int tid = threadIdx.x;
    const int tx = tid & 15, ty = tid >> 4;
    const int m0 = blockIdx.y * FBM, n0 = blockIdx.x * FBN;

    float acc[8][8];
#pragma unroll
    for (int i = 0; i < 8; ++i)
#pragma unroll
        for (int j = 0; j < 8; ++j) acc[i][j] = 0.f;

    for (int k0 = 0; k0 < K_TOTAL; k0 += FBK) {
        __syncthreads();
        if (X_TRANSPOSED) {
#pragma unroll
            for (int l = tid; l < (FBM * FBK) / 4; l += 256) {
                const int k = l >> 5, q = l & 31;
                const float4 v = *reinterpret_cast<const float4*>(
                    &X[(size_t)(k0 + k) * B_TOTAL + m0 + 4 * q]);
                *reinterpret_cast<float4*>(&sm.g.As[k][4 * q]) = v;
            }
        } else {
#pragma unroll
            for (int l = tid; l < (FBM * FBK) / 4; l += 256) {
                const int row = l >> 2, c = l & 3;
                const float4 v = *reinterpret_cast<const float4*>(
                    &X[(size_t)(m0 + row) * K_TOTAL + k0 + 4 * c]);
                sm.g.As[4 * c + 0][row] = v.x; sm.g.As[4 * c + 1][row] = v.y;
                sm.g.As[4 * c + 2][row] = v.z; sm.g.As[4 * c + 3][row] = v.w;
            }
        }
#pragma unroll
        for (int l = tid; l < (FBN * FBK) / 4; l += 256) {
            const int row = l >> 2, c = l & 3;
            const float4 v = *reinterpret_cast<const float4*>(
                &W0[(size_t)(n0 + row) * K_TOTAL + k0 + 4 * c]);
            sm.g.Bs[4 * c + 0][row] = v.x; sm.g.Bs[4 * c + 1][row] = v.y;
            sm.g.Bs[4 * c + 2][row] = v.z; sm.g.Bs[4 * c + 3][row] = v.w;
        }
        __syncthreads();
#pragma unroll
        for (int k = 0; k < FBK; ++k) {
            float a[8], bb[8];
            *reinterpret_cast<float4*>(&a[0])  = *reinterpret_cast<float4*>(&sm.g.As[k][4 * ty]);
            *reinterpret_cast<float4*>(&a[4])  = *reinterpret_cast<float4*>(&sm.g.As[k][64 + 4 * ty]);
            *reinterpret_cast<float4*>(&bb[0]) = *reinterpret_cast<float4*>(&sm.g.Bs[k][4 * tx]);
            *reinterpret_cast<float4*>(&bb[4]) = *reinterpret_cast<float4*>(&sm.g.Bs[k][64 + 4 * tx]);
#pragma unroll
            for (int i = 0; i < 8; ++i)
#pragma unroll
                for (int j = 0; j < 8; ++j) acc[i][j] += a[i] * bb[j];
        }
    }

    const int ub_base = n0 >> 3;
    for (int half = 0; half < 2; ++half) {
        __syncthreads();
#pragma unroll
        for (int i = 0; i < 8; ++i) {
            const int row = (i < 4) ? (4 * ty + i) : (64 + 4 * ty + (i - 4));
#pragma unroll
            for (int j = 0; j < 4; ++j)
                sm.Hs[row][4 * tx + j] = acc[i][4 * half + j];
        }
        __syncthreads();
#pragma unroll
        for (int p = 0; p < 4; ++p) {
            const int pair = (p << 8) + tid;
            const int ul = pair >> 7, bl = pair & 127;
            const int u = ub_base + half * 8 + ul;
            float h[HID];
#pragma unroll
            for (int j = 0; j < HID; ++j)
                h[j] = fmaxf(sm.Hs[bl][ul * 8 + j] + b0[u * 8 + j], 0.f);
            float h2[HID];
#pragma unroll
            for (int g = 0; g < HID; ++g) {
                float s = b1[u * 8 + g];
#pragma unroll
                for (int j = 0; j < HID; ++j) s += h[j] * W1[u * 64 + g * 8 + j];
                h2[g] = fmaxf(s, 0.f);
            }
            float best = b2[u * 16];
#pragma unroll
            for (int j = 0; j < HID; ++j) best += h2[j] * W2[u * 128 + j];
            int bi = 0;
#pragma unroll
            for (int a = 1; a < NACT; ++a) {
                float s = b2[u * 16 + a];
#pragma unroll
                for (int j = 0; j < HID; ++j) s += h2[j] * W2[u * 128 + a * 8 + j];
                if (s > best) { best = s; bi = a; }
            }
            outT[(size_t)u * B_TOTAL + m0 + bl] = (float)bi;
        }
    }
}

// Policy head, u-sliced: 256 blocks x 256 thr; block = 32 batch rows,
// 8 slices x 32 units each, LDS reduce. Final layer (no argmax downstream):
// reassociating the u-sum is harmless (~1e-5 on output, threshold 0.27).
__global__ __launch_bounds__(256)
void policy_kernel(const float* __restrict__ A1T,
                   const float* __restrict__ PW0, const float* __restrict__ Pb0,
                   const float* __restrict__ PW1, const float* __restrict__ Pb1,
                   const float* __restrict__ PW2, const float* __restrict__ Pb2,
                   float* __restrict__ out)
{
    __shared__ float part[8][32][HID + 1];
    const int tid = threadIdx.x;
    const int b32 = tid & 31;          // local batch row
    const int sl  = tid >> 5;          // u-slice 0..7
    const int b   = blockIdx.x * 32 + b32;

    float hp[HID];
#pragma unroll
    for (int j = 0; j < HID; ++j) hp[j] = 0.f;

#pragma unroll 1
    for (int q0 = 0; q0 < 32; q0 += 8) {
        float v[8];
#pragma unroll
        for (int t = 0; t < 8; ++t)
            v[t] = A1T[(size_t)(sl * 32 + q0 + t) * B_TOTAL + b];
#pragma unroll
        for (int t = 0; t < 8; ++t)
#pragma unroll
            for (int j = 0; j < HID; ++j)
                hp[j] += v[t] * PW0[j * U_UNITS + sl * 32 + q0 + t];
    }
#pragma unroll
    for (int j = 0; j < HID; ++j) part[sl][b32][j] = hp[j];
    __syncthreads();

    if (sl == 0) {
        float h[HID];
#pragma unroll
        for (int j = 0; j < HID; ++j) {
            float s = Pb0[j];
#pragma unroll
            for (int s8 = 0; s8 < 8; ++s8) s += part[s8][b32][j];
            h[j] = fmaxf(s, 0.f);
        }
        float h2[HID];
#pragma unroll
        for (int g = 0; g < HID; ++g) {
            float s = Pb1[g];
#pragma unroll
            for (int j = 0; j < HID; ++j) s += h[j] * PW1[g * 8 + j];
            h2[g] = fmaxf(s, 0.f);
        }
        float o = Pb2[0];
#pragma unroll
        for (int j = 0; j < HID; ++j) o += h2[j] * PW2[j];
        out[b] = o;
    }
}

// ============================================================================

extern "C" void kernel_launch(void* const* d_in, const int* in_sizes, int n_in,
                              void* d_out, int out_size, void* d_ws, size_t ws_size,
                              hipStream_t stream)
{
    const float* state = (const float*)d_in[0];
    const float* W0_0  = (const float*)d_in[1];
    const float* b0_0  = (const float*)d_in[2];
    const float* W1_0  = (const float*)d_in[3];
    const float* b1_0  = (const float*)d_in[4];
    const float* W2_0  = (const float*)d_in[5];
    const float* b2_0  = (const float*)d_in[6];
    const float* W0_1  = (const float*)d_in[7];
    const float* b0_1  = (const float*)d_in[8];
    const float* W1_1  = (const float*)d_in[9];
    const float* b1_1  = (const float*)d_in[10];
    const float* W2_1  = (const float*)d_in[11];
    const float* b2_1  = (const float*)d_in[12];
    const float* PW0   = (const float*)d_in[13];
    const float* Pb0   = (const float*)d_in[14];
    const float* PW1   = (const float*)d_in[15];
    const float* Pb1   = (const float*)d_in[16];
    const float* PW2   = (const float*)d_in[17];
    const float* Pb2   = (const float*)d_in[18];

    // ws layout (elements)
    const size_t SZ_STATE = (size_t)B_TOTAL * F_IN;
    const size_t SZ_W00   = (size_t)U_UNITS * HID * F_IN;
    const size_t SZ_W01   = (size_t)U_UNITS * HID * U_UNITS;
    const size_t NEED = (2 * SZ_STATE + 2 * SZ_W00 + 2 * SZ_W01
                         + (size_t)B_TOTAL * U_UNITS) * 2            // fp16 parts + a0
                        + (size_t)U_UNITS * B_TOTAL * 4;             // a1T fp32

    if (ws_size >= NEED) {
        char* p = (char*)d_ws;
        _Float16* state_h = (_Float16*)p;                p += SZ_STATE * 2;
        _Float16* state_l = (_Float16*)p;                p += SZ_STATE * 2;
        _Float16* w00_h   = (_Float16*)p;                p += SZ_W00 * 2;
        _Float16* w00_l   = (_Float16*)p;                p += SZ_W00 * 2;
        _Float16* w01_h   = (_Float16*)p;                p += SZ_W01 * 2;
        _Float16* w01_l   = (_Float16*)p;                p += SZ_W01 * 2;
        _Float16* a0      = (_Float16*)p;                p += (size_t)B_TOTAL * U_UNITS * 2;
        float*    a1T     = (float*)p;

        // fused pack: fp32 -> fragment-ordered fp16 (h, l*2048), one launch
        constexpr int NB0 = (B_TOTAL / 16) * (F_IN / 128);
        constexpr int NB1 = (U_UNITS * HID / 16) * (F_IN / 128);
        constexpr int NB2 = (U_UNITS * HID / 16) * (U_UNITS / 128);
        pack3_kernel<<<NB0 + NB1 + NB2, 256, 0, stream>>>(
            state, state_h, state_l, W0_0, w00_h, w00_l, W0_1, w01_h, w01_l);

        dim3 grid((U_UNITS * HID) / BN, B_TOTAL / BM);   // (32, 64)

        coagent_mfma<F_IN, true, false><<<grid, 256, 0, stream>>>(
            state_h, state_l, w00_h, w00_l, b0_0, W1_0, b1_0, W2_0, b2_0, (void*)a0);

        coagent_mfma<U_UNITS, false, true><<<grid, 256, 0, stream>>>(
            a0, nullptr, w01_h, w01_l, b0_1, W1_1, b1_1, W2_1, b2_1, (void*)a1T);

        policy_kernel<<<B_TOTAL / 32, 256, 0, stream>>>(
            a1T, PW0, Pb0, PW1, Pb1, PW2, Pb2, (float*)d_out);
    } else {
        // fp32 fallback (round-1 path, needs 16 MB ws)
        float* a0T = (float*)d_ws;
        float* a1T = a0T + (size_t)U_UNITS * B_TOTAL;
        dim3 grid((U_UNITS * HID) / FBN, B_TOTAL / FBM);
        coagent_kernel<F_IN, false><<<grid, 256, 0, stream>>>(
            state, W0_0, b0_0, W1_0, b1_0, W2_0, b2_0, a0T);
        coagent_kernel<U_UNITS, true><<<grid, 256, 0, stream>>>(
            a0T, W0_1, b0_1, W1_1, b1_1, W2_1, b2_1, a1T);
        // fallback policy path: same u-sliced kernel works on a1T [U][B]
        policy_kernel<<<B_TOTAL / 32, 256, 0, stream>>>(
            a1T, PW0, Pb0, PW1, Pb1, PW2, Pb2, (float*)d_out);
    }
}

// Round 8
// 265.150 us; speedup vs baseline: 1.1200x; 1.1200x over previous
//
#include <hip/hip_runtime.h>
#include <cstring>
#include <cstdint>

// Problem constants (fixed by reference)
#define B_TOTAL 8192
#define F_IN    1024
#define U_UNITS 256
#define NACT    16
#define HID     8

typedef float    f32x4  __attribute__((ext_vector_type(4)));
typedef _Float16 half8  __attribute__((ext_vector_type(8)));

// ============================================================================
// MFMA path: fp16 split-2 emulation of fp32 GEMM (3 passes; 2 when A exact).
// Low parts pre-scaled by 2048 (fp16 normal range). Cross terms in acc2@2^-11.
//
// R18: staging-bandwidth attack. R17 post-mortem nailed the model: total
// staged bytes (2048 blocks x 768KB = 1.5GB/dispatch over 124us = 12.6TB/s)
// saturate the L2->CU return path (~34.5TB/s aggregate ceiling); per-CU
// window = 72KB staging (~1290cy) vs 360cy MFMA -> MfmaUtil pinned at ~31-34%
// regardless of pipelining/swizzles (explains R11/R12/R14/R17 all).
// Fix: raise MFMA-per-staged-byte. Bytes/step ~ (BM+BN), MFMA ~ BM*BN:
//  * block 128x128 with 8 waves (512 thr) of 64x32 tiles -> staged bytes/step
//    unchanged (32KB) while MFMA doubles -> ceiling MfmaUtil ~47%.
//  * per-mt streaming A-fragments (af/la ephemeral, 8 live VGPRs vs 32) to
//    fit the 4-waves/SIMD register tier (<=128 incl AGPRs) -> 2 blocks/CU =
//    16 waves. Per-acc-element order still p1->p2->p3 per kt -> BIT-IDENTICAL.
//  * two-half epilogue (Hs 33KB) -> LDS = 64KB stage union.
//  * R17's m-affinity swizzle REVERTED (regressed 124->138us; L2 residency
//    unattainable at this tile size, L3 covers everything either way).
//  MFMA accumulation order and epilogue math unchanged -> absmax 0.21875.
// ============================================================================

__device__ __forceinline__ void gload_lds16(const _Float16* g, _Float16* l)
{
    // 16B per lane; LDS dest is wave-uniform base + lane*16 (HW-implicit)
    __builtin_amdgcn_global_load_lds(
        (const __attribute__((address_space(1))) void*)g,
        (__attribute__((address_space(3))) void*)l,
        16, 0, 0);
}

// fp32 [R][K] -> packed high/low fp16 [R/16][K/32][64][8]; all three tensors
// in one launch (block ranges) to save inter-dispatch gaps.
__global__ __launch_bounds__(256)
void pack3_kernel(const float* __restrict__ s0, _Float16* __restrict__ d0h, _Float16* __restrict__ d0l,
                  const float* __restrict__ s1, _Float16* __restrict__ d1h, _Float16* __restrict__ d1l,
                  const float* __restrict__ s2, _Float16* __restrict__ d2h, _Float16* __restrict__ d2l)
{
    constexpr int NB0 = (B_TOTAL / 16) * (F_IN / 128);          // 4096
    constexpr int NB1 = (U_UNITS * HID / 16) * (F_IN / 128);    // 1024
    __shared__ float ls[16 * 132];
    int b = blockIdx.x;
    const float* src; _Float16 *dh, *dl; int K, lg;
    if (b < NB0)            { src = s0; dh = d0h; dl = d0l; K = F_IN;    lg = 3; }
    else if (b < NB0 + NB1) { b -= NB0; src = s1; dh = d1h; dl = d1l; K = F_IN; lg = 3; }
    else                    { b -= NB0 + NB1; src = s2; dh = d2h; dl = d2l; K = U_UNITS; lg = 1; }

    const int tid = threadIdx.x;
    const int mt  = b >> lg;
    const int kb  = b & ((1 << lg) - 1);
    const int r0  = mt * 16;

#pragma unroll
    for (int i = 0; i < 2; ++i) {
        const int e = tid + (i << 8);
        const int row = e >> 5;
        const int c4  = e & 31;
        f32x4 v = *reinterpret_cast<const f32x4*>(
            &src[(size_t)(r0 + row) * K + (kb << 7) + (c4 << 2)]);
        *reinterpret_cast<f32x4*>(&ls[row * 132 + (c4 << 2)]) = v;
    }
    __syncthreads();

    const int k8 = tid >> 4, r = tid & 15;
    float x[8];
#pragma unroll
    for (int j = 0; j < 8; ++j) x[j] = ls[r * 132 + (k8 << 3) + j];
    half8 h, l;
#pragma unroll
    for (int j = 0; j < 8; ++j) {
        h[j] = (_Float16)x[j];
        l[j] = (_Float16)((x[j] - (float)h[j]) * 2048.0f);
    }
    const size_t off = (((size_t)mt * (K >> 5)) + (kb << 2) + (k8 >> 2)) * 512
                     + (size_t)(((k8 & 3) << 4) + r) * 8;
    *reinterpret_cast<half8*>(&dh[off]) = h;
    *reinterpret_cast<half8*>(&dl[off]) = l;
}

constexpr int BM = 128, BN = 128;   // 8 waves (512 thr), wave tile 64x32 (2M x 4N)

template<int K_TOTAL, bool A_SPLIT, bool OUT_TF32>
__global__ __launch_bounds__(512, 4)
void coagent_mfma(const _Float16* __restrict__ Ahg, const _Float16* __restrict__ Alg,
                  const _Float16* __restrict__ Bhg, const _Float16* __restrict__ Blg,
                  const float* __restrict__ b0, const float* __restrict__ W1,
                  const float* __restrict__ b1, const float* __restrict__ W2,
                  const float* __restrict__ b2, void* __restrict__ outp)
{
    // stage buffer (halves): A_SPLIT: Ah[0,4096) Al[4096,8192) Bh[8192,12288)
    // Bl[12288,16384). !A_SPLIT: Ah[0,4096) Bh[4096,8192) Bl[8192,12288).
    constexpr int BUFH  = A_SPLIT ? 16384 : 12288;
    constexpr int BOFFH = A_SPLIT ? 8192 : 4096;
    constexpr int BOFFL = A_SPLIT ? 12288 : 8192;
    constexpr int NCH   = A_SPLIT ? 4 : 3;      // staging chunks per wave (8 waves)

    struct EpiBufs { float Hs[BM][65]; _Float16 ab[BM * 8]; };
    union SMemU { _Float16 stage[2][BUFH]; EpiBufs epi; };
    __shared__ SMemU sm;

    constexpr int NTK = K_TOTAL >> 5;        // k-tiles (K=32 each); 32 or 8
    constexpr size_t TS = (size_t)NTK * 512; // halves per row-tile

    const int tid  = threadIdx.x;
    const int wave = tid >> 6;               // 0..7
    const int lane = tid & 63;
    const int quad = lane >> 4;
    const int l15  = lane & 15;

    const int m0 = blockIdx.y * BM;
    const int n0 = blockIdx.x * BN;

    const int wmi = wave >> 2;               // 0..1 (M)
    const int wni = wave & 3;                // 0..3 (N)
    const int at  = wmi * 4;                 // A subtile base (of 8)
    const int bt  = wni * 2;                 // B subtile base (of 8)
    const int wm  = wmi * 64;

    // ---- staging chunk map: NCH chunks per wave. Bases wave-uniform
    // (readfirstlane) -> SGPR arithmetic; lane offset added at call sites.
    const int wave_u = __builtin_amdgcn_readfirstlane(wave);
    const _Float16* gs[NCH];
#pragma unroll
    for (int i = 0; i < NCH; ++i) {
        const int c = wave_u * NCH + i;
        const _Float16* base; int tile;
        if (A_SPLIT) {
            if (c < 8)       { base = Ahg; tile = (m0 >> 4) + c; }
            else if (c < 16) { base = Alg; tile = (m0 >> 4) + (c - 8); }
            else if (c < 24) { base = Bhg; tile = (n0 >> 4) + (c - 16); }
            else             { base = Blg; tile = (n0 >> 4) + (c - 24); }
        } else {
            if (c < 8)       { base = Ahg; tile = (m0 >> 4) + c; }
            else if (c < 16) { base = Bhg; tile = (n0 >> 4) + (c - 8); }
            else             { base = Blg; tile = (n0 >> 4) + (c - 16); }
        }
        gs[i] = base + (size_t)tile * TS;
    }
    const int loff = lane * 8;   // element offset (16B per lane)

    f32x4 acc1[4][2];   // Ah*Bh            (scale 1)
    f32x4 acc2[4][2];   // Al'*Bh + Ah*Bl'  (scale 2^-11)
#pragma unroll
    for (int i = 0; i < 4; ++i)
#pragma unroll
        for (int jj = 0; jj < 2; ++jj) { acc1[i][jj] = {0.f,0.f,0.f,0.f}; acc2[i][jj] = {0.f,0.f,0.f,0.f}; }

    // prologue: stage k-tile 0 into buffer 0
#pragma unroll
    for (int i = 0; i < NCH; ++i)
        gload_lds16(gs[i] + loff, &sm.stage[0][(wave_u * NCH + i) * 512]);
    __syncthreads();

    int cur = 0;
#pragma unroll 1
    for (int kt = 0; kt < NTK; ++kt) {
        // issue next tile's staging loads (in flight across the MFMA phase)
        if (kt + 1 < NTK) {
            _Float16* nb = &sm.stage[cur ^ 1][0];
#pragma unroll
            for (int i = 0; i < NCH; ++i)
                gload_lds16(gs[i] + (size_t)(kt + 1) * 512 + loff,
                            nb + (wave_u * NCH + i) * 512);
        }

        const _Float16* sb = &sm.stage[cur][0];
        // B fragments resident for the step (16 VGPRs)
        half8 bf[2], lb[2];
#pragma unroll
        for (int nt = 0; nt < 2; ++nt) {
            bf[nt] = *reinterpret_cast<const half8*>(&sb[BOFFH + (bt + nt) * 512 + lane * 8]);
            lb[nt] = *reinterpret_cast<const half8*>(&sb[BOFFL + (bt + nt) * 512 + lane * 8]);
        }
        // A fragments streamed per-mt (8 live VGPRs). Per-acc-element order
        // remains pass1 -> pass2 -> pass3 within kt -> bit-identical.
#pragma unroll
        for (int mt = 0; mt < 4; ++mt) {
            half8 af = *reinterpret_cast<const half8*>(&sb[(at + mt) * 512 + lane * 8]);
#pragma unroll
            for (int nt = 0; nt < 2; ++nt)
                acc1[mt][nt] = __builtin_amdgcn_mfma_f32_16x16x32_f16(af, bf[nt], acc1[mt][nt], 0, 0, 0);
            if constexpr (A_SPLIT) {
                half8 la = *reinterpret_cast<const half8*>(&sb[4096 + (at + mt) * 512 + lane * 8]);
#pragma unroll
                for (int nt = 0; nt < 2; ++nt)
                    acc2[mt][nt] = __builtin_amdgcn_mfma_f32_16x16x32_f16(la, bf[nt], acc2[mt][nt], 0, 0, 0);
            }
#pragma unroll
            for (int nt = 0; nt < 2; ++nt)
                acc2[mt][nt] = __builtin_amdgcn_mfma_f32_16x16x32_f16(af, lb[nt], acc2[mt][nt], 0, 0, 0);
        }

        __syncthreads();   // stage(kt+1) complete + all reads of buf cur done
        cur ^= 1;
    }

    // ---- epilogue: two 64-col halves (8 units each). N-waves {0,1} own
    // half 0 (cols 0-63), {2,3} own half 1 (cols 64-127).
    const int ubase = n0 >> 3;
    for (int half = 0; half < 2; ++half) {
        __syncthreads();
        if ((wni >> 1) == half) {
#pragma unroll
            for (int mt = 0; mt < 4; ++mt)
#pragma unroll
                for (int nt = 0; nt < 2; ++nt)
#pragma unroll
                    for (int r = 0; r < 4; ++r)
                        sm.epi.Hs[wm + mt * 16 + quad * 4 + r][(wni & 1) * 32 + nt * 16 + l15] =
                            acc1[mt][nt][r] + acc2[mt][nt][r] * (1.0f / 2048.0f);
        }
        __syncthreads();
#pragma unroll
        for (int p = 0; p < 2; ++p) {
            const int idx = (p << 9) + tid;     // 512 threads x 2 = 1024 items
            const int ul = idx >> 7;            // unit 0..7, wave-uniform
            const int bl = idx & 127;           // lane-consecutive batch row
            // pin u as wave-uniform -> weight loads become scalar (SMEM pipe)
            const int u  = __builtin_amdgcn_readfirstlane(ubase + half * 8 + ul);
            const float* __restrict__ b0u = b0 + u * 8;
            const float* __restrict__ W1u = W1 + u * 64;
            const float* __restrict__ b1u = b1 + u * 8;
            const float* __restrict__ W2u = W2 + u * 128;
            const float* __restrict__ b2u = b2 + u * 16;

            float h[HID];
#pragma unroll
            for (int jj = 0; jj < HID; ++jj)
                h[jj] = fmaxf(sm.epi.Hs[bl][ul * 8 + jj] + b0u[jj], 0.f);

            float h2[HID];
#pragma unroll
            for (int g = 0; g < HID; ++g) {
                float s = b1u[g];
#pragma unroll
                for (int jj = 0; jj < HID; ++jj)
                    s += h[jj] * W1u[g * 8 + jj];
                h2[g] = fmaxf(s, 0.f);
            }

            float best = b2u[0];
#pragma unroll
            for (int jj = 0; jj < HID; ++jj) best += h2[jj] * W2u[jj];
            int bi = 0;
#pragma unroll
            for (int a = 1; a < NACT; ++a) {
                float s = b2u[a];
#pragma unroll
                for (int jj = 0; jj < HID; ++jj)
                    s += h2[jj] * W2u[a * 8 + jj];
                if (s > best) { best = s; bi = a; }   // first-max-wins = np.argmax
            }

            if (OUT_TF32) {
                ((float*)outp)[(size_t)u * B_TOTAL + m0 + bl] = (float)bi;
            } else {
                sm.epi.ab[bl * 8 + ul] = (_Float16)bi;
            }
        }
        if (!OUT_TF32) {
            __syncthreads();
            if (tid < 128) {   // write a0 in PACKED layout (NTK=8 for K=256)
                float4 v = *reinterpret_cast<float4*>(&sm.epi.ab[tid * 8]);
                const int u = ubase + half * 8;          // octet base, uniform
                const int b = m0 + tid;
                const size_t off = ((size_t)(b >> 4) * 8 + (u >> 5)) * 512
                                 + (size_t)((((u >> 3) & 3) << 4) + (b & 15)) * 8;
                *reinterpret_cast<float4*>(&((_Float16*)outp)[off]) = v;
            }
        }
    }
}

// ============================================================================
// fp32 fallback path (round-1 kernels) — used only if ws_size is too small
// ============================================================================

constexpr int FBM = 128, FBN = 128, FBK = 16;

template<int K_TOTAL, bool X_TRANSPOSED>
__global__ __launch_bounds__(256, 2)
void coagent_kernel(const float* __restrict__ X, const float* __restrict__ W0,
                    const float* __restrict__ b0, const float* __restrict__ W1,
                    const float* __restrict__ b1, const float* __restrict__ W2,
                    const float* __restrict__ b2, float* __restrict__ outT)
{
    struct SMemGemm { float As[FBK][FBM + 4]; float Bs[FBK][FBN + 4]; };
    union SMem { SMemGemm g; float Hs[FBM][65]; };
    __shared__ SMem sm;

    const int tid = threadIdx.x;
    const int tx = tid & 15, ty = tid >> 4;
    const int m0 = blockIdx.y * FBM, n0 = blockIdx.x * FBN;

    float acc[8][8];
#pragma unroll
    for (int i = 0; i < 8; ++i)
#pragma unroll
        for (int j = 0; j < 8; ++j) acc[i][j] = 0.f;

    for (int k0 = 0; k0 < K_TOTAL; k0 += FBK) {
        __syncthreads();
        if (X_TRANSPOSED) {
#pragma unroll
            for (int l = tid; l < (FBM * FBK) / 4; l += 256) {
                const int k = l >> 5, q = l & 31;
                const float4 v = *reinterpret_cast<const float4*>(
                    &X[(size_t)(k0 + k) * B_TOTAL + m0 + 4 * q]);
                *reinterpret_cast<float4*>(&sm.g.As[k][4 * q]) = v;
            }
        } else {
#pragma unroll
            for (int l = tid; l < (FBM * FBK) / 4; l += 256) {
                const int row = l >> 2, c = l & 3;
                const float4 v = *reinterpret_cast<const float4*>(
                    &X[(size_t)(m0 + row) * K_TOTAL + k0 + 4 * c]);
                sm.g.As[4 * c + 0][row] = v.x; sm.g.As[4 * c + 1][row] = v.y;
                sm.g.As[4 * c + 2][row] = v.z; sm.g.As[4 * c + 3][row] = v.w;
            }
        }
#pragma unroll
        for (int l = tid; l < (FBN * FBK) / 4; l += 256) {
            const int row = l >> 2, c = l & 3;
            const float4 v = *reinterpret_cast<const float4*>(
                &W0[(size_t)(n0 + row) * K_TOTAL + k0 + 4 * c]);
            sm.g.Bs[4 * c + 0][row] = v.x; sm.g.Bs[4 * c + 1][row] = v.y;
            sm.g.Bs[4 * c + 2][row] = v.z; sm.g.Bs[4 * c + 3][row] = v.w;
        }
        __syncthreads();
#pragma unroll
        for (int k = 0; k < FBK; ++k) {
            float a[8], bb[8];
            *reinterpret_cast<float4*>(&a[0])  = *reinterpret_cast<float4*>(&sm.g.As[k][4 * ty]);
            *reinterpret_cast<float4*>(&a[4])  = *reinterpret_cast<float4*>(&sm.g.As[k][64 + 4 * ty]);
            *reinterpret_cast<float4*>(&bb[0]) = *reinterpret_cast<float4*>(&sm.g.Bs[k][4 * tx]);
            *reinterpret_cast<float4*>(&bb[4]) = *reinterpret_cast<float4*>(&sm.g.Bs[k][64 + 4 * tx]);
#pragma unroll
            for (int i = 0; i < 8; ++i)
#pragma unroll
                for (int j = 0; j < 8; ++j) acc[i][j] += a[i] * bb[j];
        }
    }

    const int ub_base = n0 >> 3;
    for (int half = 0; half < 2; ++half) {
        __syncthreads();
#pragma unroll
        for (int i = 0; i < 8; ++i) {
            const int row = (i < 4) ? (4 * ty + i) : (64 + 4 * ty + (i - 4));
#pragma unroll
            for (int j = 0; j < 4; ++j)
                sm.Hs[row][4 * tx + j] = acc[i][4 * half + j];
        }
        __syncthreads();
#pragma unroll
        for (int p = 0; p < 4; ++p) {
            const int pair = (p << 8) + tid;
            const int ul = pair >> 7, bl = pair & 127;
            const int u = ub_base + half * 8 + ul;
            float h[HID];
#pragma unroll
            for (int j = 0; j < HID; ++j)
                h[j] = fmaxf(sm.Hs[bl][ul * 8 + j] + b0[u * 8 + j], 0.f);
            float h2[HID];
#pragma unroll
            for (int g = 0; g < HID; ++g) {
                float s = b1[u * 8 + g];
#pragma unroll
                for (int j = 0; j < HID; ++j) s += h[j] * W1[u * 64 + g * 8 + j];
                h2[g] = fmaxf(s, 0.f);
            }
            float best = b2[u * 16];
#pragma unroll
            for (int j = 0; j < HID; ++j) best += h2[j] * W2[u * 128 + j];
            int bi = 0;
#pragma unroll
            for (int a = 1; a < NACT; ++a) {
                float s = b2[u * 16 + a];
#pragma unroll
                for (int j = 0; j < HID; ++j) s += h2[j] * W2[u * 128 + a * 8 + j];
                if (s > best) { best = s; bi = a; }
            }
            outT[(size_t)u * B_TOTAL + m0 + bl] = (float)bi;
        }
    }
}

// Policy head, u-sliced: 256 blocks x 256 thr; block = 32 batch rows,
// 8 slices x 32 units each, LDS reduce. Final layer (no argmax downstream):
// reassociating the u-sum is harmless (~1e-5 on output, threshold 0.27).
__global__ __launch_bounds__(256)
void policy_kernel(const float* __restrict__ A1T,
                   const float* __restrict__ PW0, const float* __restrict__ Pb0,
                   const float* __restrict__ PW1, const float* __restrict__ Pb1,
                   const float* __restrict__ PW2, const float* __restrict__ Pb2,
                   float* __restrict__ out)
{
    __shared__ float part[8][32][HID + 1];
    const int tid = threadIdx.x;
    const int b32 = tid & 31;          // local batch row
    const int sl  = tid >> 5;          // u-slice 0..7
    const int b   = blockIdx.x * 32 + b32;

    float hp[HID];
#pragma unroll
    for (int j = 0; j < HID; ++j) hp[j] = 0.f;

#pragma unroll 1
    for (int q0 = 0; q0 < 32; q0 += 8) {
        float v[8];
#pragma unroll
        for (int t = 0; t < 8; ++t)
            v[t] = A1T[(size_t)(sl * 32 + q0 + t) * B_TOTAL + b];
#pragma unroll
        for (int t = 0; t < 8; ++t)
#pragma unroll
            for (int j = 0; j < HID; ++j)
                hp[j] += v[t] * PW0[j * U_UNITS + sl * 32 + q0 + t];
    }
#pragma unroll
    for (int j = 0; j < HID; ++j) part[sl][b32][j] = hp[j];
    __syncthreads();

    if (sl == 0) {
        float h[HID];
#pragma unroll
        for (int j = 0; j < HID; ++j) {
            float s = Pb0[j];
#pragma unroll
            for (int s8 = 0; s8 < 8; ++s8) s += part[s8][b32][j];
            h[j] = fmaxf(s, 0.f);
        }
        float h2[HID];
#pragma unroll
        for (int g = 0; g < HID; ++g) {
            float s = Pb1[g];
#pragma unroll
            for (int j = 0; j < HID; ++j) s += h[j] * PW1[g * 8 + j];
            h2[g] = fmaxf(s, 0.f);
        }
        float o = Pb2[0];
#pragma unroll
        for (int j = 0; j < HID; ++j) o += h2[j] * PW2[j];
        out[b] = o;
    }
}

// ============================================================================

extern "C" void kernel_launch(void* const* d_in, const int* in_sizes, int n_in,
                              void* d_out, int out_size, void* d_ws, size_t ws_size,
                              hipStream_t stream)
{
    const float* state = (const float*)d_in[0];
    const float* W0_0  = (const float*)d_in[1];
    const float* b0_0  = (const float*)d_in[2];
    const float* W1_0  = (const float*)d_in[3];
    const float* b1_0  = (const float*)d_in[4];
    const float* W2_0  = (const float*)d_in[5];
    const float* b2_0  = (const float*)d_in[6];
    const float* W0_1  = (const float*)d_in[7];
    const float* b0_1  = (const float*)d_in[8];
    const float* W1_1  = (const float*)d_in[9];
    const float* b1_1  = (const float*)d_in[10];
    const float* W2_1  = (const float*)d_in[11];
    const float* b2_1  = (const float*)d_in[12];
    const float* PW0   = (const float*)d_in[13];
    const float* Pb0   = (const float*)d_in[14];
    const float* PW1   = (const float*)d_in[15];
    const float* Pb1   = (const float*)d_in[16];
    const float* PW2   = (const float*)d_in[17];
    const float* Pb2   = (const float*)d_in[18];

    // ws layout (elements)
    const size_t SZ_STATE = (size_t)B_TOTAL * F_IN;
    const size_t SZ_W00   = (size_t)U_UNITS * HID * F_IN;
    const size_t SZ_W01   = (size_t)U_UNITS * HID * U_UNITS;
    const size_t NEED = (2 * SZ_STATE + 2 * SZ_W00 + 2 * SZ_W01
                         + (size_t)B_TOTAL * U_UNITS) * 2            // fp16 parts + a0
                        + (size_t)U_UNITS * B_TOTAL * 4;             // a1T fp32

    if (ws_size >= NEED) {
        char* p = (char*)d_ws;
        _Float16* state_h = (_Float16*)p;                p += SZ_STATE * 2;
        _Float16* state_l = (_Float16*)p;                p += SZ_STATE * 2;
        _Float16* w00_h   = (_Float16*)p;                p += SZ_W00 * 2;
        _Float16* w00_l   = (_Float16*)p;                p += SZ_W00 * 2;
        _Float16* w01_h   = (_Float16*)p;                p += SZ_W01 * 2;
        _Float16* w01_l   = (_Float16*)p;                p += SZ_W01 * 2;
        _Float16* a0      = (_Float16*)p;                p += (size_t)B_TOTAL * U_UNITS * 2;
        float*    a1T     = (float*)p;

        // fused pack: fp32 -> fragment-ordered fp16 (h, l*2048), one launch
        constexpr int NB0 = (B_TOTAL / 16) * (F_IN / 128);
        constexpr int NB1 = (U_UNITS * HID / 16) * (F_IN / 128);
        constexpr int NB2 = (U_UNITS * HID / 16) * (U_UNITS / 128);
        pack3_kernel<<<NB0 + NB1 + NB2, 256, 0, stream>>>(
            state, state_h, state_l, W0_0, w00_h, w00_l, W0_1, w01_h, w01_l);

        dim3 grid((U_UNITS * HID) / BN, B_TOTAL / BM);   // (16, 64)

        coagent_mfma<F_IN, true, false><<<grid, 512, 0, stream>>>(
            state_h, state_l, w00_h, w00_l, b0_0, W1_0, b1_0, W2_0, b2_0, (void*)a0);

        coagent_mfma<U_UNITS, false, true><<<grid, 512, 0, stream>>>(
            a0, nullptr, w01_h, w01_l, b0_1, W1_1, b1_1, W2_1, b2_1, (void*)a1T);

        policy_kernel<<<B_TOTAL / 32, 256, 0, stream>>>(
            a1T, PW0, Pb0, PW1, Pb1, PW2, Pb2, (float*)d_out);
    } else {
        // fp32 fallback (round-1 path, needs 16 MB ws)
        float* a0T = (float*)d_ws;
        float* a1T = a0T + (size_t)U_UNITS * B_TOTAL;
        dim3 grid((U_UNITS * HID) / FBN, B_TOTAL / FBM);
        coagent_kernel<F_IN, false><<<grid, 256, 0, stream>>>(
            state, W0_0, b0_0, W1_0, b1_0, W2_0, b2_0, a0T);
        coagent_kernel<U_UNITS, true><<<grid, 256, 0, stream>>>(
            a0T, W0_1, b0_1, W1_1, b1_1, W2_1, b2_1, a1T);
        // fallback policy path: same u-sliced kernel works on a1T [U][B]
        policy_kernel<<<B_TOTAL / 32, 256, 0, stream>>>(
            a1T, PW0, Pb0, PW1, Pb1, PW2, Pb2, (float*)d_out);
    }
}